// Round 7
// baseline (1123.374 us; speedup 1.0000x reference)
//
#include <hip/hip_runtime.h>
#include <hip/hip_bf16.h>
#include <string.h>

// GNN layer, round 6 resubmit (round-6 bench died on container acquisition,
// not on the kernel): own-sorted visit list + segmented REGISTER accumulation.
//   Counting-sort (exact node id) the 2E visits (own,oth,eid); unified msg:
//        H[own] += lrelu(A[oth] + B[own] + C[e]) @ We2
//   edge_sorted (64 visits/block):
//     - visit records + ef rows gathered (128B random, small)
//     - A[oth]/B[own] preloaded in 8-row register batches AHEAD of use
//       (16-32 outstanding 256B loads/wave: MLP-deepening)
//     - C = ef@Wet MFMA -> Ms; msg built in-place; Y = Ms@We2t MFMA
//     - sorted rows => consecutive rows share own: accumulate Y in fp32
//       REGISTERS per lane, ONE pk-atomic row per run (~160k rows vs 1M)
//   Round-2 lesson: no concurrent LDS atomics on sorted keys (registers only).
//   Round-4 lesson: no fragment-layout random gathers (row-major via LDS).
// Evidence: rounds 0/1/5 all pinned at 429-430us while atomic ops halved and
// bytes fell 32% -> wall is random row-touch count / gather latency; this
// round cuts touches 3M->2.2M and deepens read MLP.

using f32x4  = __attribute__((ext_vector_type(4))) float;
using bf16x8 = __attribute__((ext_vector_type(8))) short;

#define P128 132   // K=128 LDS tile pitch (264 B)
#define P256 264   // K=256 LDS tile pitch (528 B)
#define YROW 132
#define VPB  64    // visits per block

__device__ __forceinline__ float lrelu(float x) { return x >= 0.f ? x : 0.01f * x; }

__device__ __forceinline__ ushort f2bf(float f) {
    union { float f; unsigned u; } v; v.f = f;
    unsigned u = v.u;
    return (ushort)((u + 0x7fffu + ((u >> 16) & 1u)) >> 16);   // RNE
}
__device__ __forceinline__ float bf2f(ushort u) {
    union { unsigned u; float f; } v; v.u = ((unsigned)u) << 16; return v.f;
}

__device__ __forceinline__ void atomic_pk_add_bf16(void* addr, unsigned val) {
    asm volatile("global_atomic_pk_add_bf16 %0, %1, off" : : "v"(addr), "v"(val) : "memory");
}

// ---------------- AB GEMM: X staged once, W frags from global ----------------
__global__ __launch_bounds__(256) void gemm_ab(
    const ushort* __restrict__ X,     // [Np,128] bf16
    const ushort* __restrict__ Wt,    // [512,128] bf16
    ushort* __restrict__ out)         // [Np,512] bf16
{
    __shared__ ushort Xs[128 * P128];
    const int tid  = threadIdx.x;
    const int lane = tid & 63;
    const int wv   = tid >> 6;
    const int wm   = wv >> 1, wn = wv & 1;
    const int row0 = blockIdx.x * 128;

    #pragma unroll
    for (int q = 0; q < 8; ++q) {
        int idx = q * 256 + tid;
        int r = idx >> 4, c = idx & 15;
        *reinterpret_cast<uint4*>(&Xs[r * P128 + c * 8]) =
            *reinterpret_cast<const uint4*>(X + (size_t)(row0 + r) * 128 + c * 8);
    }
    __syncthreads();

    const int g8 = (lane >> 4) * 8;
    for (int cb = 0; cb < 4; ++cb) {
        f32x4 acc[4][4] = {};
        #pragma unroll
        for (int ks = 0; ks < 4; ++ks) {
            bf16x8 af[4], bf[4];
            #pragma unroll
            for (int i = 0; i < 4; ++i) {
                int mrow = wm * 64 + i * 16 + (lane & 15);
                af[i] = *reinterpret_cast<const bf16x8*>(&Xs[mrow * P128 + ks * 32 + g8]);
                int nc = cb * 128 + wn * 64 + i * 16 + (lane & 15);
                bf[i] = *reinterpret_cast<const bf16x8*>(Wt + (size_t)nc * 128 + ks * 32 + g8);
            }
            #pragma unroll
            for (int i = 0; i < 4; ++i)
                #pragma unroll
                for (int j = 0; j < 4; ++j)
                    acc[i][j] = __builtin_amdgcn_mfma_f32_16x16x32_bf16(af[i], bf[j], acc[i][j], 0, 0, 0);
        }
        #pragma unroll
        for (int i = 0; i < 4; ++i) {
            int gr0 = row0 + wm * 64 + i * 16 + ((lane >> 4) << 2);
            #pragma unroll
            for (int j = 0; j < 4; ++j) {
                int gc = cb * 128 + wn * 64 + j * 16 + (lane & 15);
                #pragma unroll
                for (int r = 0; r < 4; ++r)
                    out[(size_t)(gr0 + r) * 512 + gc] = f2bf(acc[i][j][r]);
            }
        }
    }
}

// ---------------- binning: counting sort of visits by own node ----------------
__global__ __launch_bounds__(256) void ebin_count(
    const int* __restrict__ src, const int* __restrict__ dst,
    int* __restrict__ cnt, int E)
{
    int i = blockIdx.x * 256 + threadIdx.x;
    if (i >= E) return;
    atomicAdd(&cnt[dst[i]], 1);
    atomicAdd(&cnt[src[i]], 1);
}

// exclusive scan over cnt[0..n) -> cur[0..n). 1 block, 256 threads.
__global__ __launch_bounds__(256) void escan(
    const int* __restrict__ cnt, int* __restrict__ cur, int n)
{
    __shared__ int ps[256];
    const int t = threadIdx.x;
    const int per = (n + 255) / 256;
    int s = 0;
    for (int i = 0; i < per; ++i) { int idx = t * per + i; if (idx < n) s += cnt[idx]; }
    ps[t] = s;
    __syncthreads();
    for (int off = 1; off < 256; off <<= 1) {
        int u = (t >= off) ? ps[t - off] : 0;
        __syncthreads();
        ps[t] += u;
        __syncthreads();
    }
    int run = ps[t] - s;
    for (int i = 0; i < per; ++i) {
        int idx = t * per + i;
        if (idx < n) { cur[idx] = run; run += cnt[idx]; }
    }
}

// scatter visit records {own, oth, eid} sorted by own (single 16B store each)
__global__ __launch_bounds__(256) void escatter(
    const int* __restrict__ src, const int* __restrict__ dst,
    int* __restrict__ cur, int4* __restrict__ vrec, int E)
{
    int i = blockIdx.x * 256 + threadIdx.x;
    if (i >= E) return;
    int s_ = src[i], d_ = dst[i];
    int p1 = atomicAdd(&cur[d_], 1);
    vrec[p1] = make_int4(d_, s_, i, 0);        // forward: own=dst, oth=src
    int p2 = atomicAdd(&cur[s_], 1);
    vrec[p2] = make_int4(s_, d_, i, 0);        // backward: own=src, oth=dst
}

// ---------------- sorted edge pass: segmented register accumulation ----------
// 64 visits/block, 256 threads. LDS = Ms 33.8K + efs 9.2K + rec 0.8K = 43.8K
// -> 3 blocks/CU. Wave wv owns msg rows wv*16..+15 (sorted by own).
__global__ __launch_bounds__(256) void edge_sorted(
    const ushort* __restrict__ efb,   // [Ep,64] bf16
    const ushort* __restrict__ Wet,   // [256,64] bf16, n-major (We1_e^T)
    const ushort* __restrict__ We2t,  // [128,256] bf16, n-major (We2^T)
    const ushort* __restrict__ AB,    // [Np,512] bf16: row = [A(256)|B(256)]
    const int4* __restrict__ vrec,    // [NV] {own, oth, eid} sorted by own
    ushort* __restrict__ H,           // [Np,128] bf16 accumulator
    int NV)
{
    __shared__ ushort Ms[VPB * P256];      // C tile -> msg tile; Ys aliases front
    __shared__ ushort efs[VPB * 72];
    __shared__ int so[VPB], st_[VPB], se[VPB];

    const int tid  = threadIdx.x;
    const int lane = tid & 63;
    const int wv   = tid >> 6;             // 0..3
    const int g8   = (lane >> 4) * 8;
    const int v0   = blockIdx.x * VPB;

    if (tid < VPB) {
        int v = v0 + tid;
        if (v < NV) { int4 r = vrec[v]; so[tid] = r.x; st_[tid] = r.y; se[tid] = r.z; }
        else        { so[tid] = -1; st_[tid] = 0; se[tid] = 0; }
    }
    __syncthreads();

    // ---- batch-0 A/B preload (rows wv*16+0..7): 32 loads in flight ----
    ushort2 av0[8][2], bv0[8][2];
    #pragma unroll
    for (int u = 0; u < 8; ++u) {
        int m = wv * 16 + u;
        int oth = st_[m];
        int own = so[m] < 0 ? 0 : so[m];
        #pragma unroll
        for (int h = 0; h < 2; ++h) {
            av0[u][h] = *(const ushort2*)(AB + (size_t)oth * 512 + h * 128 + lane * 2);
            bv0[u][h] = *(const ushort2*)(AB + (size_t)own * 512 + 256 + h * 128 + lane * 2);
        }
    }

    // ---- ef gather (64 rows x 128B, row-major into LDS) ----
    #pragma unroll
    for (int q = 0; q < 2; ++q) {
        int row = q * 32 + (tid >> 3);
        *reinterpret_cast<uint4*>(&efs[row * 72 + (tid & 7) * 8]) =
            *reinterpret_cast<const uint4*>(efb + (size_t)se[row] * 64 + (tid & 7) * 8);
    }
    __syncthreads();

    // ---- C = efs @ Wet : [64 x 256] -> Ms; wave owns col quarter wv*64 ----
    {
        f32x4 ac[4][4] = {};
        #pragma unroll
        for (int ks = 0; ks < 2; ++ks) {
            bf16x8 af[4], bf[4];
            #pragma unroll
            for (int i = 0; i < 4; ++i) {
                int er = i * 16 + (lane & 15);
                af[i] = *reinterpret_cast<const bf16x8*>(&efs[er * 72 + ks * 32 + g8]);
            }
            #pragma unroll
            for (int j = 0; j < 4; ++j) {
                int nc = wv * 64 + j * 16 + (lane & 15);
                bf[j] = *reinterpret_cast<const bf16x8*>(Wet + (size_t)nc * 64 + ks * 32 + g8);
            }
            #pragma unroll
            for (int i = 0; i < 4; ++i)
                #pragma unroll
                for (int j = 0; j < 4; ++j)
                    ac[i][j] = __builtin_amdgcn_mfma_f32_16x16x32_bf16(af[i], bf[j], ac[i][j], 0, 0, 0);
        }
        // C/D layout: col = lane&15, row = (lane>>4)*4 + reg
        #pragma unroll
        for (int i = 0; i < 4; ++i) {
            int er0 = i * 16 + ((lane >> 4) << 2);
            #pragma unroll
            for (int j = 0; j < 4; ++j) {
                int fc = wv * 64 + j * 16 + (lane & 15);
                #pragma unroll
                for (int r = 0; r < 4; ++r)
                    Ms[(er0 + r) * P256 + fc] = f2bf(ac[i][j][r]);
            }
        }
    }
    __syncthreads();

    // ---- msg build in-place on Ms (wave rows only -> no cross-wave race) ----
    // batch-1 preload issued FIRST so its latency hides under batch-0 compute
    ushort2 av1[8][2], bv1[8][2];
    #pragma unroll
    for (int u = 0; u < 8; ++u) {
        int m = wv * 16 + 8 + u;
        int oth = st_[m];
        int own = so[m] < 0 ? 0 : so[m];
        #pragma unroll
        for (int h = 0; h < 2; ++h) {
            av1[u][h] = *(const ushort2*)(AB + (size_t)oth * 512 + h * 128 + lane * 2);
            bv1[u][h] = *(const ushort2*)(AB + (size_t)own * 512 + 256 + h * 128 + lane * 2);
        }
    }
    #pragma unroll
    for (int u = 0; u < 8; ++u) {
        int m = wv * 16 + u;
        #pragma unroll
        for (int h = 0; h < 2; ++h) {
            int c = h * 128 + lane * 2;
            ushort2 cv = *(const ushort2*)(&Ms[m * P256 + c]);
            ushort2 mv;
            mv.x = f2bf(lrelu(bf2f(av0[u][h].x) + bf2f(bv0[u][h].x) + bf2f(cv.x)));
            mv.y = f2bf(lrelu(bf2f(av0[u][h].y) + bf2f(bv0[u][h].y) + bf2f(cv.y)));
            *(ushort2*)(&Ms[m * P256 + c]) = mv;
        }
    }
    #pragma unroll
    for (int u = 0; u < 8; ++u) {
        int m = wv * 16 + 8 + u;
        #pragma unroll
        for (int h = 0; h < 2; ++h) {
            int c = h * 128 + lane * 2;
            ushort2 cv = *(const ushort2*)(&Ms[m * P256 + c]);
            ushort2 mv;
            mv.x = f2bf(lrelu(bf2f(av1[u][h].x) + bf2f(bv1[u][h].x) + bf2f(cv.x)));
            mv.y = f2bf(lrelu(bf2f(av1[u][h].y) + bf2f(bv1[u][h].y) + bf2f(cv.y)));
            *(ushort2*)(&Ms[m * P256 + c]) = mv;
        }
    }
    __syncthreads();

    // ---- Y = Ms @ We2t : [64 x 128], K=256 ----
    const int wm = wv >> 1, wn = wv & 1;
    f32x4 ay[2][4] = {};
    #pragma unroll
    for (int ks = 0; ks < 8; ++ks) {
        bf16x8 af[2], bf[4];
        #pragma unroll
        for (int i = 0; i < 2; ++i) {
            int mrow = wm * 32 + i * 16 + (lane & 15);
            af[i] = *reinterpret_cast<const bf16x8*>(&Ms[mrow * P256 + ks * 32 + g8]);
        }
        #pragma unroll
        for (int j = 0; j < 4; ++j) {
            int nc = wn * 64 + j * 16 + (lane & 15);
            bf[j] = *reinterpret_cast<const bf16x8*>(We2t + (size_t)nc * 256 + ks * 32 + g8);
        }
        #pragma unroll
        for (int i = 0; i < 2; ++i)
            #pragma unroll
            for (int j = 0; j < 4; ++j)
                ay[i][j] = __builtin_amdgcn_mfma_f32_16x16x32_bf16(af[i], bf[j], ay[i][j], 0, 0, 0);
    }
    __syncthreads();       // ALL Ms reads done before aliasing writes

    ushort* Ys = Ms;       // [64][YROW] occupies front of Ms
    #pragma unroll
    for (int i = 0; i < 2; ++i) {
        int yr0 = wm * 32 + i * 16 + ((lane >> 4) << 2);
        #pragma unroll
        for (int j = 0; j < 4; ++j) {
            int yc = wn * 64 + j * 16 + (lane & 15);
            #pragma unroll
            for (int r = 0; r < 4; ++r)
                Ys[(yr0 + r) * YROW + yc] = f2bf(ay[i][j][r]);
        }
    }
    __syncthreads();

    // ---- segmented scatter: fp32 run accumulation, 1 atomic row per run ----
    {
        float a0 = 0.f, a1 = 0.f;
        int cur = so[wv * 16];
        #pragma unroll 4
        for (int q = 0; q < 16; ++q) {
            int row = wv * 16 + q;
            int own = so[row];                 // wave-uniform
            ushort2 yv = *(const ushort2*)(&Ys[row * YROW + lane * 2]);
            float y0 = bf2f(yv.x), y1 = bf2f(yv.y);
            if (own != cur) {
                if (cur >= 0) {
                    ushort2 o; o.x = f2bf(a0); o.y = f2bf(a1);
                    unsigned uv; memcpy(&uv, &o, 4);
                    atomic_pk_add_bf16(H + (size_t)cur * 128 + lane * 2, uv);
                }
                cur = own; a0 = y0; a1 = y1;
            } else { a0 += y0; a1 += y1; }
        }
        if (cur >= 0) {
            ushort2 o; o.x = f2bf(a0); o.y = f2bf(a1);
            unsigned uv; memcpy(&uv, &o, 4);
            atomic_pk_add_bf16(H + (size_t)cur * 128 + lane * 2, uv);
        }
    }
}

// ---------------- fused MLP tail: [nf|H] -> hid -> out ----------------
__global__ __launch_bounds__(256) void mlp_fused(
    const ushort* __restrict__ H,     // [Np,128] bf16 (= red)
    const ushort* __restrict__ nfb,   // [Np,128] bf16
    const ushort* __restrict__ Wn1t,  // [256,256] bf16 n-major
    const ushort* __restrict__ Wn2t,  // [128,256] bf16 n-major
    float* __restrict__ out, int Nreal)
{
    __shared__ ushort lds[128 * P256];
    ushort* Ns  = lds;
    ushort* Rs  = lds + 128 * P128;
    ushort* Hid = lds;

    const int tid  = threadIdx.x;
    const int lane = tid & 63;
    const int wv   = tid >> 6;
    const int wm   = wv >> 1, wn = wv & 1;
    const int row0 = blockIdx.x * 128;
    const int g8   = (lane >> 4) * 8;

    #pragma unroll
    for (int q = 0; q < 8; ++q) {
        int idx = q * 256 + tid;
        int r = idx >> 4, c = (idx & 15) * 8;
        *reinterpret_cast<uint4*>(&Ns[r * P128 + c]) =
            *reinterpret_cast<const uint4*>(nfb + (size_t)(row0 + r) * 128 + c);
        *reinterpret_cast<uint4*>(&Rs[r * P128 + c]) =
            *reinterpret_cast<const uint4*>(H + (size_t)(row0 + r) * 128 + c);
    }
    __syncthreads();

    f32x4 a2[2][4][4] = {};
    #pragma unroll
    for (int cb = 0; cb < 2; ++cb) {
        #pragma unroll
        for (int ks = 0; ks < 8; ++ks) {
            bf16x8 af[4], bf[4];
            #pragma unroll
            for (int i = 0; i < 4; ++i) {
                int mrow = wm * 64 + i * 16 + (lane & 15);
                af[i] = (ks < 4)
                    ? *reinterpret_cast<const bf16x8*>(&Ns[mrow * P128 + ks * 32 + g8])
                    : *reinterpret_cast<const bf16x8*>(&Rs[mrow * P128 + (ks - 4) * 32 + g8]);
                int nc = cb * 128 + wn * 64 + i * 16 + (lane & 15);
                bf[i] = *reinterpret_cast<const bf16x8*>(Wn1t + (size_t)nc * 256 + ks * 32 + g8);
            }
            #pragma unroll
            for (int i = 0; i < 4; ++i)
                #pragma unroll
                for (int j = 0; j < 4; ++j)
                    a2[cb][i][j] = __builtin_amdgcn_mfma_f32_16x16x32_bf16(af[i], bf[j], a2[cb][i][j], 0, 0, 0);
        }
    }
    __syncthreads();

    #pragma unroll
    for (int cb = 0; cb < 2; ++cb)
        #pragma unroll
        for (int i = 0; i < 4; ++i) {
            int er0 = wm * 64 + i * 16 + ((lane >> 4) << 2);
            #pragma unroll
            for (int j = 0; j < 4; ++j) {
                int fc = cb * 128 + wn * 64 + j * 16 + (lane & 15);
                #pragma unroll
                for (int r = 0; r < 4; ++r)
                    Hid[(er0 + r) * P256 + fc] = f2bf(lrelu(a2[cb][i][j][r]));
            }
        }
    __syncthreads();

    f32x4 a3[4][4] = {};
    #pragma unroll
    for (int ks = 0; ks < 8; ++ks) {
        bf16x8 af[4], bf[4];
        #pragma unroll
        for (int i = 0; i < 4; ++i) {
            int mrow = wm * 64 + i * 16 + (lane & 15);
            af[i] = *reinterpret_cast<const bf16x8*>(&Hid[mrow * P256 + ks * 32 + g8]);
            int nc = wn * 64 + i * 16 + (lane & 15);
            bf[i] = *reinterpret_cast<const bf16x8*>(Wn2t + (size_t)nc * 256 + ks * 32 + g8);
        }
        #pragma unroll
        for (int i = 0; i < 4; ++i)
            #pragma unroll
            for (int j = 0; j < 4; ++j)
                a3[i][j] = __builtin_amdgcn_mfma_f32_16x16x32_bf16(af[i], bf[j], a3[i][j], 0, 0, 0);
    }
    #pragma unroll
    for (int i = 0; i < 4; ++i) {
        int gr0 = row0 + wm * 64 + i * 16 + ((lane >> 4) << 2);
        #pragma unroll
        for (int j = 0; j < 4; ++j) {
            int gc = wn * 64 + j * 16 + (lane & 15);
            #pragma unroll
            for (int r = 0; r < 4; ++r) {
                int gr = gr0 + r;
                if (gr < Nreal) out[(size_t)gr * 128 + gc] = a3[i][j][r];
            }
        }
    }
}

// float -> bf16 with zero padding; n_real, n_pad multiples of 4
__global__ __launch_bounds__(256) void cvt_pad(
    const float* __restrict__ x, ushort* __restrict__ y, size_t n_real, size_t n_pad)
{
    size_t i = ((size_t)blockIdx.x * 256 + threadIdx.x) * 4;
    if (i >= n_pad) return;
    ushort4 o;
    if (i < n_real) {
        float4 v = *(const float4*)(x + i);
        o.x = f2bf(v.x); o.y = f2bf(v.y); o.z = f2bf(v.z); o.w = f2bf(v.w);
    } else { o.x = 0; o.y = 0; o.z = 0; o.w = 0; }
    *(ushort4*)(y + i) = o;
}

// transpose + convert all weights to bf16 [N,K] layouts
__global__ __launch_bounds__(256) void wcvt(
    const float* __restrict__ We1, const float* __restrict__ We2,
    const float* __restrict__ Wn1, const float* __restrict__ Wn2,
    ushort* __restrict__ Wabt, ushort* __restrict__ Wet, ushort* __restrict__ We2t,
    ushort* __restrict__ Wn1t, ushort* __restrict__ Wn2t)
{
    int idx = blockIdx.x * 256 + threadIdx.x;
    switch (blockIdx.y) {
    case 0: if (idx < 256*128) { int n = idx >> 7, k = idx & 127; Wabt[idx]            = f2bf(We1[k * 256 + n]); } break;
    case 1: if (idx < 256*128) { int n = idx >> 7, k = idx & 127; Wabt[32768 + idx]    = f2bf(We1[(128 + k) * 256 + n]); } break;
    case 2: if (idx < 256*64)  { int n = idx >> 6, k = idx & 63;  Wet[idx]             = f2bf(We1[(256 + k) * 256 + n]); } break;
    case 3: if (idx < 128*256) { int n = idx >> 8, k = idx & 255; We2t[idx]            = f2bf(We2[k * 128 + n]); } break;
    case 4: if (idx < 256*256) { int n = idx >> 8, k = idx & 255; Wn1t[idx]            = f2bf(Wn1[k * 256 + n]); } break;
    case 5: if (idx < 128*256) { int n = idx >> 8, k = idx & 255; Wn2t[idx]            = f2bf(Wn2[k * 128 + n]); } break;
    }
}

extern "C" void kernel_launch(void* const* d_in, const int* in_sizes, int n_in,
                              void* d_out, int out_size, void* d_ws, size_t ws_size,
                              hipStream_t stream) {
    const float* nf  = (const float*)d_in[0];
    const float* ef  = (const float*)d_in[1];
    const int*   src = (const int*)d_in[2];
    const int*   dst = (const int*)d_in[3];
    const float* We1 = (const float*)d_in[4];
    const float* We2 = (const float*)d_in[5];
    const float* Wn1 = (const float*)d_in[6];
    const float* Wn2 = (const float*)d_in[7];
    float* out = (float*)d_out;

    const int  N  = in_sizes[0] / 128;            // 100000
    const int  E  = in_sizes[2];                  // 500000
    const int  Np = (N + 127) & ~127;             // 100096
    const long Ep = ((long)E + 127) & ~127L;      // 500096
    const int  NV = 2 * E;                        // 1,000,000 visits

    char* p = (char*)d_ws;
    auto alloc = [&](size_t bytes) { char* r = p; p += (bytes + 255) & ~(size_t)255; return r; };
    ushort* AB   = (ushort*)alloc((size_t)Np * 512 * 2);
    ushort* H    = (ushort*)alloc((size_t)Np * 128 * 2);   // [Np,128] bf16 (= red)
    ushort* nfb  = (ushort*)alloc((size_t)Np * 128 * 2);
    ushort* efb  = (ushort*)alloc((size_t)Ep * 64 * 2);
    ushort* Wabt = (ushort*)alloc(65536 * 2);
    ushort* Wet  = (ushort*)alloc(16384 * 2);
    ushort* We2t = (ushort*)alloc(32768 * 2);
    ushort* Wn1t = (ushort*)alloc(65536 * 2);
    ushort* Wn2t = (ushort*)alloc(32768 * 2);
    int*    cnt  = (int*)alloc((size_t)N * 4);
    int*    curp = (int*)alloc((size_t)N * 4);
    int4*   vrec = (int4*)alloc((size_t)NV * 16);

    dim3 blk(256);
    const unsigned egrid = (unsigned)((E + 255) / 256);

    wcvt<<<dim3(256, 6), blk, 0, stream>>>(We1, We2, Wn1, Wn2, Wabt, Wet, We2t, Wn1t, Wn2t);
    cvt_pad<<<dim3((unsigned)((size_t)Np * 128 / 1024)), blk, 0, stream>>>(nf, nfb, (size_t)N * 128, (size_t)Np * 128);
    cvt_pad<<<dim3((unsigned)((size_t)Ep * 64 / 1024)), blk, 0, stream>>>(ef, efb, (size_t)E * 64, (size_t)Ep * 64);

    // counting sort of visits by own node
    hipMemsetAsync(cnt, 0, (size_t)N * 4, stream);
    ebin_count<<<dim3(egrid), blk, 0, stream>>>(src, dst, cnt, E);
    escan<<<dim3(1), blk, 0, stream>>>(cnt, curp, N);
    escatter<<<dim3(egrid), blk, 0, stream>>>(src, dst, curp, vrec, E);

    // AB = nf @ [We1_s | We1_d]
    gemm_ab<<<dim3(Np / 128), blk, 0, stream>>>(nfb, Wabt, AB);

    hipMemsetAsync(H, 0, (size_t)Np * 128 * 2, stream);

    // sorted edge pass: segmented register accumulation (~10M pk-atomics)
    edge_sorted<<<dim3((unsigned)((NV + VPB - 1) / VPB)), blk, 0, stream>>>(
        efb, Wet, We2t, AB, vrec, H, NV);

    // hid = lrelu([nf|H] @ Wn1); out = hid @ Wn2
    mlp_fused<<<dim3(Np / 128), blk, 0, stream>>>(H, nfb, Wn1t, Wn2t, out, N);
}